// Round 4
// baseline (65.727 us; speedup 1.0000x reference)
//
#include <hip/hip_runtime.h>
#include <hip/hip_fp16.h>

// O = U X U^H, U = kron of 11 single-qubit SU(2) gates (2048^2 complex64).
// Each transform = 11 radix-2 butterfly stages. Two kernels:
//   colpass: W = U X        (butterfly over row index, 4-column strips)
//   rowpass: O = rows of W transformed by conj(U) (butterfly over col index)
// Per kernel: 3 register phases, 16 elems/thread (bits 7-10 from global,
// bits 3-6, bits 0-2 via LDS exchanges). 512 blocks x 512 threads => 2
// resident blocks/CU for load/compute overlap (round-3 was 1 block/CU,
// fully serialized). W intermediate is fp16 (half2) = 16 MB, L2/L3-resident.
// LDS: split Re/Im fp32 planes, addr = 4r+c+4*(r>>4): 2 lanes/bank (free)
// for all phases. Traffic ~64 MB, target ~25-35 us.

#define DIM 2048
#define NQ 11
#define LPLANE 8704  // 4*2047+3+4*127 = 8699 -> padded plane size (floats)

__device__ __forceinline__ int lidx(int r, int c) {
    return (r << 2) + c + ((r >> 4) << 2);
}

__device__ __forceinline__ float2 cmul(float2 a, float2 b) {
    return make_float2(a.x * b.x - a.y * b.y, a.x * b.y + a.y * b.x);
}

// Composite gate g = Rz @ Ry @ Rx for qubit q; conj!=0 -> conjugate entries.
__device__ __forceinline__ void make_gate(const float* __restrict__ w, int q,
                                          int conj, float2* out4) {
    const float WM = 0.632455532033675866f;  // sqrt(2/5)
    float hx = 0.5f * WM * w[q * 3 + 0];
    float hy = 0.5f * WM * w[q * 3 + 1];
    float hz = 0.5f * WM * w[q * 3 + 2];
    float cx, sx, cy, sy, cz, sz;
    sincosf(hx, &sx, &cx);
    sincosf(hy, &sy, &cy);
    sincosf(hz, &sz, &cz);
    float2 m00 = make_float2(cy * cx,  sy * sx);
    float2 m01 = make_float2(-sy * cx, -cy * sx);
    float2 m10 = make_float2(sy * cx,  -cy * sx);
    float2 m11 = make_float2(cy * cx,  -sy * sx);
    float2 ez  = make_float2(cz, -sz);
    float2 ezc = make_float2(cz,  sz);
    float2 g00 = cmul(ez, m00);
    float2 g01 = cmul(ez, m01);
    float2 g10 = cmul(ezc, m10);
    float2 g11 = cmul(ezc, m11);
    float sgn = conj ? -1.f : 1.f;
    out4[0] = make_float2(g00.x, sgn * g00.y);
    out4[1] = make_float2(g01.x, sgn * g01.y);
    out4[2] = make_float2(g10.x, sgn * g10.y);
    out4[3] = make_float2(g11.x, sgn * g11.y);
}

__device__ __forceinline__ void bfly(float2& A, float2& B, const float2* g) {
    float2 a = A, b = B;
    A = make_float2(g[0].x * a.x - g[0].y * a.y + g[1].x * b.x - g[1].y * b.y,
                    g[0].x * a.y + g[0].y * a.x + g[1].x * b.y + g[1].y * b.x);
    B = make_float2(g[2].x * a.x - g[2].y * a.y + g[3].x * b.x - g[3].y * b.y,
                    g[2].x * a.y + g[2].y * a.x + g[3].x * b.y + g[3].y * b.x);
}

template <int ST>
__device__ __forceinline__ void stage16(float2* v, const float2* g) {
#pragma unroll
    for (int m = 0; m < 16; ++m)
        if (!(m & ST)) bfly(v[m], v[m + ST], g);
}

__device__ __forceinline__ void load_gate(const float2 (*gsh)[4], int q,
                                          float2* g) {
    g[0] = gsh[q][0]; g[1] = gsh[q][1]; g[2] = gsh[q][2]; g[3] = gsh[q][3];
}

__device__ __forceinline__ unsigned pack_h2(float2 v) {
    __half2 h = __float22half2_rn(v);
    return *reinterpret_cast<unsigned*>(&h);
}
__device__ __forceinline__ float2 unpack_h2(unsigned u) {
    __half2 h = *reinterpret_cast<__half2*>(&u);
    return __half22float2(h);
}

// ---------------- K1: W = U X (column transform, 4-col strip) --------------
// W layout: strip-blocked half2, W[blk*8192 + c*2048 + r].
__global__ __launch_bounds__(512, 4) void colpass(
    const float* __restrict__ X, unsigned* __restrict__ W,
    const float* __restrict__ wt) {
    __shared__ float ldsRe[LPLANE];
    __shared__ float ldsIm[LPLANE];
    __shared__ float2 gsh[NQ][4];
    int t = threadIdx.x;
    if (t < NQ) make_gate(wt, t, 0, &gsh[t][0]);
    __syncthreads();

    int c = t & 3, u = t >> 2;          // u in 0..127
    int c0 = blockIdx.x * 4;

    // Phase A: r = u + 128m (bits 7..10 -> qubits 3,2,1,0). X real.
    float xr[16];
#pragma unroll
    for (int m = 0; m < 16; ++m)
        xr[m] = X[(size_t)(u + (m << 7)) * DIM + c0 + c];

    float2 v[16], g[4];
    load_gate(gsh, 3, g);               // bit 7, real-input stage
#pragma unroll
    for (int m = 0; m < 16; m += 2) {
        float a = xr[m], b = xr[m + 1];
        v[m]     = make_float2(g[0].x * a + g[1].x * b, g[0].y * a + g[1].y * b);
        v[m + 1] = make_float2(g[2].x * a + g[3].x * b, g[2].y * a + g[3].y * b);
    }
    load_gate(gsh, 2, g); stage16<2>(v, g);   // bit 8
    load_gate(gsh, 1, g); stage16<4>(v, g);   // bit 9
    load_gate(gsh, 0, g); stage16<8>(v, g);   // bit 10

#pragma unroll
    for (int m = 0; m < 16; ++m) {
        int a = lidx(u + (m << 7), c);
        ldsRe[a] = v[m].x; ldsIm[a] = v[m].y;
    }
    __syncthreads();

    // Phase M: r = (u&7) + 8m + 128*(u>>3) (bits 3..6 -> qubits 7,6,5,4).
    int uLo = u & 7, uHi = u >> 3;
#pragma unroll
    for (int m = 0; m < 16; ++m) {
        int a = lidx(uLo + (m << 3) + (uHi << 7), c);
        v[m] = make_float2(ldsRe[a], ldsIm[a]);
    }
    load_gate(gsh, 7, g); stage16<1>(v, g);
    load_gate(gsh, 6, g); stage16<2>(v, g);
    load_gate(gsh, 5, g); stage16<4>(v, g);
    load_gate(gsh, 4, g); stage16<8>(v, g);
#pragma unroll
    for (int m = 0; m < 16; ++m) {
        int a = lidx(uLo + (m << 3) + (uHi << 7), c);
        ldsRe[a] = v[m].x; ldsIm[a] = v[m].y;
    }
    __syncthreads();

    // Phase F: r = m + 16u (bits 0..2 -> qubits 10,9,8).
#pragma unroll
    for (int m = 0; m < 16; ++m) {
        int a = lidx(m + (u << 4), c);
        v[m] = make_float2(ldsRe[a], ldsIm[a]);
    }
    load_gate(gsh, 10, g); stage16<1>(v, g);
    load_gate(gsh, 9, g);  stage16<2>(v, g);
    load_gate(gsh, 8, g);  stage16<4>(v, g);

    // Store fp16, r = 16u + m consecutive per thread -> packed uint4.
    unsigned* wp = W + (size_t)blockIdx.x * 8192 + c * 2048 + (u << 4);
#pragma unroll
    for (int e = 0; e < 4; ++e) {
        uint4 pk;
        pk.x = pack_h2(v[4 * e + 0]);
        pk.y = pack_h2(v[4 * e + 1]);
        pk.z = pack_h2(v[4 * e + 2]);
        pk.w = pack_h2(v[4 * e + 3]);
        *reinterpret_cast<uint4*>(wp + 4 * e) = pk;
    }
}

// ------------- K2: O rows = conj(U) along columns j of W -------------------
__global__ __launch_bounds__(512, 4) void rowpass(
    const unsigned* __restrict__ W, float* __restrict__ Out,
    const float* __restrict__ wt, int writeComplex) {
    __shared__ float ldsRe[LPLANE];
    __shared__ float ldsIm[LPLANE];
    __shared__ float2 gsh[NQ][4];
    int t = threadIdx.x;
    if (t < NQ) make_gate(wt, t, 1, &gsh[t][0]);  // conjugated gates
    __syncthreads();

    int rv = t & 3, u = t >> 2;         // u in 0..127
    int r0 = blockIdx.x * 4;

    // Phase A: j = u + 128m; W elem (r,j) at (j>>2)*8192 + (j&3)*2048 + r.
    int jb = u >> 2, jl = u & 3;
    float2 v[16], g[4];
#pragma unroll
    for (int m = 0; m < 16; ++m)
        v[m] = unpack_h2(
            W[(size_t)(jb + (m << 5)) * 8192 + jl * 2048 + r0 + rv]);

    load_gate(gsh, 3, g); stage16<1>(v, g);   // j bit 7
    load_gate(gsh, 2, g); stage16<2>(v, g);   // j bit 8
    load_gate(gsh, 1, g); stage16<4>(v, g);   // j bit 9
    load_gate(gsh, 0, g); stage16<8>(v, g);   // j bit 10
#pragma unroll
    for (int m = 0; m < 16; ++m) {
        int a = lidx(u + (m << 7), rv);
        ldsRe[a] = v[m].x; ldsIm[a] = v[m].y;
    }
    __syncthreads();

    // Phase M: j = (u&7) + 8m + 128*(u>>3) (bits 3..6 -> qubits 7,6,5,4).
    int uLo = u & 7, uHi = u >> 3;
#pragma unroll
    for (int m = 0; m < 16; ++m) {
        int a = lidx(uLo + (m << 3) + (uHi << 7), rv);
        v[m] = make_float2(ldsRe[a], ldsIm[a]);
    }
    load_gate(gsh, 7, g); stage16<1>(v, g);
    load_gate(gsh, 6, g); stage16<2>(v, g);
    load_gate(gsh, 5, g); stage16<4>(v, g);
    load_gate(gsh, 4, g); stage16<8>(v, g);
#pragma unroll
    for (int m = 0; m < 16; ++m) {
        int a = lidx(uLo + (m << 3) + (uHi << 7), rv);
        ldsRe[a] = v[m].x; ldsIm[a] = v[m].y;
    }
    __syncthreads();

    // Phase F: j = m + 16u (bits 0..2 -> qubits 10,9,8).
#pragma unroll
    for (int m = 0; m < 16; ++m) {
        int a = lidx(m + (u << 4), rv);
        v[m] = make_float2(ldsRe[a], ldsIm[a]);
    }
    load_gate(gsh, 10, g); stage16<1>(v, g);
    load_gate(gsh, 9, g);  stage16<2>(v, g);
    load_gate(gsh, 8, g);  stage16<4>(v, g);

    // Thread holds j = 16u..16u+15 of row r0+rv.
    if (!writeComplex) {
        float* op = Out + (size_t)(r0 + rv) * DIM + (u << 4);
#pragma unroll
        for (int e = 0; e < 4; ++e)
            *reinterpret_cast<float4*>(op + 4 * e) =
                make_float4(v[4 * e].x, v[4 * e + 1].x,
                            v[4 * e + 2].x, v[4 * e + 3].x);
    } else {
        float2* o2 = (float2*)Out + (size_t)(r0 + rv) * DIM + (u << 4);
#pragma unroll
        for (int m = 0; m < 16; ++m) o2[m] = v[m];
    }
}

extern "C" void kernel_launch(void* const* d_in, const int* in_sizes, int n_in,
                              void* d_out, int out_size, void* d_ws,
                              size_t ws_size, hipStream_t stream) {
    const float* X = (const float*)d_in[0];
    const float* wt = (const float*)d_in[1];
    float* out = (float*)d_out;
    unsigned* W = (unsigned*)d_ws;  // 2048^2 half2 = 16 MB

    colpass<<<DIM / 4, 512, 0, stream>>>(X, W, wt);
    int wc = (out_size >= 2 * DIM * DIM) ? 1 : 0;
    rowpass<<<DIM / 4, 512, 0, stream>>>(W, out, wt, wc);
}

// Round 5
// 44.855 us; speedup vs baseline: 1.4653x; 1.4653x over previous
//
#include <hip/hip_runtime.h>
#include <hip/hip_fp16.h>

// O = U X U^H, U = kron of 11 single-qubit SU(2) gates (2048^2 complex64).
// Reordered as O = U * (X * U^H):
//   K1 rowpass : Y = X U^H  (butterflies over col index j, conj gates)
//                4 rows x 2048 cols per block, 3 register phases,
//                fp32 split-plane LDS with XOR swizzle j^((j>>5)&31)
//                (2-way bank access in all phases). Y stored fp16.
//   K2 collow  : col-transform bits 0-6 of row idx (qubits 10..4),
//                128x32 tiles, 2 phases, 1 barrier. Z stored fp16.
//   K3 colhigh : col-transform bits 7-10 (qubits 3..0), registers only,
//                rows at stride 128, writes Re(O) fp32.
// All global accesses 128-256 B per wave-instruction (no overfetch).
// Traffic ~96 MB total; FMA floor ~10 us; target ~25-32 us.

#define DIM 2048
#define NQ 11

__device__ __forceinline__ int swz(int j) { return j ^ ((j >> 5) & 31); }

__device__ __forceinline__ float2 cmul(float2 a, float2 b) {
    return make_float2(a.x * b.x - a.y * b.y, a.x * b.y + a.y * b.x);
}

// Composite gate g = Rz @ Ry @ Rx for qubit q; conj!=0 -> conjugate entries.
__device__ __forceinline__ void make_gate(const float* __restrict__ w, int q,
                                          int conj, float2* out4) {
    const float WM = 0.632455532033675866f;  // sqrt(2/5)
    float hx = 0.5f * WM * w[q * 3 + 0];
    float hy = 0.5f * WM * w[q * 3 + 1];
    float hz = 0.5f * WM * w[q * 3 + 2];
    float cx, sx, cy, sy, cz, sz;
    sincosf(hx, &sx, &cx);
    sincosf(hy, &sy, &cy);
    sincosf(hz, &sz, &cz);
    float2 m00 = make_float2(cy * cx,  sy * sx);
    float2 m01 = make_float2(-sy * cx, -cy * sx);
    float2 m10 = make_float2(sy * cx,  -cy * sx);
    float2 m11 = make_float2(cy * cx,  -sy * sx);
    float2 ez  = make_float2(cz, -sz);
    float2 ezc = make_float2(cz,  sz);
    float2 g00 = cmul(ez, m00);
    float2 g01 = cmul(ez, m01);
    float2 g10 = cmul(ezc, m10);
    float2 g11 = cmul(ezc, m11);
    float sgn = conj ? -1.f : 1.f;
    out4[0] = make_float2(g00.x, sgn * g00.y);
    out4[1] = make_float2(g01.x, sgn * g01.y);
    out4[2] = make_float2(g10.x, sgn * g10.y);
    out4[3] = make_float2(g11.x, sgn * g11.y);
}

__device__ __forceinline__ void bfly(float2& A, float2& B, const float2* g) {
    float2 a = A, b = B;
    A = make_float2(g[0].x * a.x - g[0].y * a.y + g[1].x * b.x - g[1].y * b.y,
                    g[0].x * a.y + g[0].y * a.x + g[1].x * b.y + g[1].y * b.x);
    B = make_float2(g[2].x * a.x - g[2].y * a.y + g[3].x * b.x - g[3].y * b.y,
                    g[2].x * a.y + g[2].y * a.x + g[3].x * b.y + g[3].y * b.x);
}

template <int ST>
__device__ __forceinline__ void stage16(float2* v, const float2* g) {
#pragma unroll
    for (int m = 0; m < 16; ++m)
        if (!(m & ST)) bfly(v[m], v[m + ST], g);
}

__device__ __forceinline__ void load_gate(const float2 (*gsh)[4], int q,
                                          float2* g) {
    g[0] = gsh[q][0]; g[1] = gsh[q][1]; g[2] = gsh[q][2]; g[3] = gsh[q][3];
}

__device__ __forceinline__ unsigned pack_h2(float2 v) {
    __half2 h = __float22half2_rn(v);
    return *reinterpret_cast<unsigned*>(&h);
}
__device__ __forceinline__ float2 unpack_h2(unsigned u) {
    __half2 h = *reinterpret_cast<__half2*>(&u);
    return __half22float2(h);
}

// ---------------- K1: Y = X U^H (row transform, 4 rows/block) --------------
__global__ __launch_bounds__(512, 4) void rowpassK1(
    const float* __restrict__ X, unsigned* __restrict__ Y,
    const float* __restrict__ wt) {
    __shared__ float pRe[4 * DIM];
    __shared__ float pIm[4 * DIM];
    __shared__ float2 gsh[NQ][4];
    int t = threadIdx.x;
    if (t < NQ) make_gate(wt, t, 1, &gsh[t][0]);  // conjugated gates
    __syncthreads();

    int u = t & 127, rv = t >> 7;       // u = j bits 0-6
    int row = blockIdx.x * 4 + rv;
    const float* xrow = X + (size_t)row * DIM;
    int base = rv * DIM;

    // Phase A: j = u + 128m (bits 7-10 -> qubits 3,2,1,0). X real.
    float xr[16];
#pragma unroll
    for (int m = 0; m < 16; ++m) xr[m] = xrow[u + (m << 7)];

    float2 v[16], g[4];
    load_gate(gsh, 3, g);               // j bit 7, real-input stage
#pragma unroll
    for (int m = 0; m < 16; m += 2) {
        float a = xr[m], b = xr[m + 1];
        v[m]     = make_float2(g[0].x * a + g[1].x * b, g[0].y * a + g[1].y * b);
        v[m + 1] = make_float2(g[2].x * a + g[3].x * b, g[2].y * a + g[3].y * b);
    }
    load_gate(gsh, 2, g); stage16<2>(v, g);   // bit 8
    load_gate(gsh, 1, g); stage16<4>(v, g);   // bit 9
    load_gate(gsh, 0, g); stage16<8>(v, g);   // bit 10

#pragma unroll
    for (int m = 0; m < 16; ++m) {
        int a = base + swz(u + (m << 7));
        pRe[a] = v[m].x; pIm[a] = v[m].y;
    }
    __syncthreads();

    // Phase M: j = (u&7) + 8m + 128*(u>>3) (bits 3-6 -> qubits 7,6,5,4).
    int uLo = u & 7, uHi = u >> 3;
#pragma unroll
    for (int m = 0; m < 16; ++m) {
        int a = base + swz(uLo + (m << 3) + (uHi << 7));
        v[m] = make_float2(pRe[a], pIm[a]);
    }
    load_gate(gsh, 7, g); stage16<1>(v, g);
    load_gate(gsh, 6, g); stage16<2>(v, g);
    load_gate(gsh, 5, g); stage16<4>(v, g);
    load_gate(gsh, 4, g); stage16<8>(v, g);
#pragma unroll
    for (int m = 0; m < 16; ++m) {
        int a = base + swz(uLo + (m << 3) + (uHi << 7));
        pRe[a] = v[m].x; pIm[a] = v[m].y;
    }
    __syncthreads();

    // Phase F: j = m + 16u (bits 0-2 -> qubits 10,9,8).
#pragma unroll
    for (int m = 0; m < 16; ++m) {
        int a = base + swz(m + (u << 4));
        v[m] = make_float2(pRe[a], pIm[a]);
    }
    load_gate(gsh, 10, g); stage16<1>(v, g);
    load_gate(gsh, 9, g);  stage16<2>(v, g);
    load_gate(gsh, 8, g);  stage16<4>(v, g);

    // Store fp16: thread holds 16 consecutive j = 16u..16u+15.
    unsigned* yp = Y + (size_t)row * DIM + (u << 4);
#pragma unroll
    for (int e = 0; e < 4; ++e) {
        uint4 pk;
        pk.x = pack_h2(v[4 * e + 0]);
        pk.y = pack_h2(v[4 * e + 1]);
        pk.z = pack_h2(v[4 * e + 2]);
        pk.w = pack_h2(v[4 * e + 3]);
        *reinterpret_cast<uint4*>(yp + 4 * e) = pk;
    }
}

// -------- K2: column transform over row bits 0-6 (qubits 10..4) ------------
// Tile: 128 rows x 32 cols. 256 threads, 16 elems each, 2 phases.
__global__ __launch_bounds__(256, 4) void collowK2(
    const unsigned* __restrict__ Y, unsigned* __restrict__ Z,
    const float* __restrict__ wt) {
    __shared__ float pRe[128 * 32];
    __shared__ float pIm[128 * 32];
    __shared__ float2 gsh[NQ][4];
    int t = threadIdx.x;
    if (t < NQ) make_gate(wt, t, 0, &gsh[t][0]);
    __syncthreads();

    int c = t & 31, rr = t >> 5;        // rr = d bits 0-2 (phase A)
    int r0 = (blockIdx.x >> 6) * 128;   // row group (16)
    int c0 = (blockIdx.x & 63) * 32;    // col group (64)

    // Phase A: d = rr + 8m (bits 3-6 -> qubits 7,6,5,4).
    float2 v[16], g[4];
#pragma unroll
    for (int m = 0; m < 16; ++m)
        v[m] = unpack_h2(Y[(size_t)(r0 + rr + (m << 3)) * DIM + c0 + c]);

    load_gate(gsh, 7, g); stage16<1>(v, g);
    load_gate(gsh, 6, g); stage16<2>(v, g);
    load_gate(gsh, 5, g); stage16<4>(v, g);
    load_gate(gsh, 4, g); stage16<8>(v, g);
#pragma unroll
    for (int m = 0; m < 16; ++m) {
        int a = (rr + (m << 3)) * 32 + c;
        pRe[a] = v[m].x; pIm[a] = v[m].y;
    }
    __syncthreads();

    // Phase F: d = m + 16rr (bits 0-2 -> qubits 10,9,8).
#pragma unroll
    for (int m = 0; m < 16; ++m) {
        int a = (m + (rr << 4)) * 32 + c;
        v[m] = make_float2(pRe[a], pIm[a]);
    }
    load_gate(gsh, 10, g); stage16<1>(v, g);
    load_gate(gsh, 9, g);  stage16<2>(v, g);
    load_gate(gsh, 8, g);  stage16<4>(v, g);

#pragma unroll
    for (int m = 0; m < 16; ++m)
        Z[(size_t)(r0 + m + (rr << 4)) * DIM + c0 + c] = pack_h2(v[m]);
}

// -------- K3: column transform over row bits 7-10 (qubits 3..0) ------------
// No LDS: thread owns rows d + 128m for one column j. Writes Re(O) fp32.
__global__ __launch_bounds__(512, 4) void colhighK3(
    const unsigned* __restrict__ Z, float* __restrict__ Out,
    const float* __restrict__ wt, int writeComplex) {
    __shared__ float2 gsh[NQ][4];
    int t = threadIdx.x;
    if (t < NQ) make_gate(wt, t, 0, &gsh[t][0]);
    __syncthreads();

    int b = blockIdx.x;
    int j = (b & 31) * 64 + (t & 63);
    int d = (b >> 5) * 8 + (t >> 6);    // row bits 0-6

    float2 v[16], g[4];
#pragma unroll
    for (int m = 0; m < 16; ++m)
        v[m] = unpack_h2(Z[(size_t)(d + (m << 7)) * DIM + j]);

    load_gate(gsh, 3, g); stage16<1>(v, g);   // row bit 7
    load_gate(gsh, 2, g); stage16<2>(v, g);   // bit 8
    load_gate(gsh, 1, g); stage16<4>(v, g);   // bit 9
    load_gate(gsh, 0, g); stage16<8>(v, g);   // bit 10

    if (!writeComplex) {
#pragma unroll
        for (int m = 0; m < 16; ++m)
            Out[(size_t)(d + (m << 7)) * DIM + j] = v[m].x;
    } else {
        float2* o2 = (float2*)Out;
#pragma unroll
        for (int m = 0; m < 16; ++m)
            o2[(size_t)(d + (m << 7)) * DIM + j] = v[m];
    }
}

extern "C" void kernel_launch(void* const* d_in, const int* in_sizes, int n_in,
                              void* d_out, int out_size, void* d_ws,
                              size_t ws_size, hipStream_t stream) {
    const float* X = (const float*)d_in[0];
    const float* wt = (const float*)d_in[1];
    float* out = (float*)d_out;
    unsigned* Y = (unsigned*)d_ws;                          // 16 MB fp16
    unsigned* Z = (unsigned*)((char*)d_ws + (size_t)DIM * DIM * 4);  // 16 MB

    rowpassK1<<<DIM / 4, 512, 0, stream>>>(X, Y, wt);
    collowK2<<<16 * 64, 256, 0, stream>>>(Y, Z, wt);
    int wc = (out_size >= 2 * DIM * DIM) ? 1 : 0;
    colhighK3<<<512, 512, 0, stream>>>(Z, out, wt, wc);
}